// Round 6
// baseline (136.471 us; speedup 1.0000x reference)
//
#include <hip/hip_runtime.h>
#include <stdint.h>

typedef _Float16 half8 __attribute__((ext_vector_type(8)));
typedef _Float16 half4 __attribute__((ext_vector_type(4)));
typedef __fp16   fp16x2 __attribute__((ext_vector_type(2)));
typedef float    floatx4 __attribute__((ext_vector_type(4)));
typedef unsigned uintx2 __attribute__((ext_vector_type(2)));

#define T_LEN 2048
#define CH 64
#define BH 32            // bs * n_heads
#define QTILE 64         // t per block (shared by all 4 waves; waves partition s)
#define LDP 72           // prep LDS pad (halves)
#define FRAG_BH 131072   // halves per bh per tensor (64*2048)

// ---------------- pass 1: fp32 -> fp16, reorder into MFMA fragment order ----------
// Q pre-scaled by 0.125 * rescale * log2(e) so attention does raw exp2.
// QF/KF[bh][g][ks][lane][8]: g = t(or s)>>4, element = X[c = ks*32+quad*8+j][t = g*16+l15]
// VF[bh][sl][ct][lane][4]  (16x16x16 A-frag order):
//   element = V[c = ct*16 + l15][s = sl*16 + quad*4 + e]
__global__ __launch_bounds__(256, 2)
void prep_kernel(const float* __restrict__ qkv, const float* __restrict__ rescale,
                 _Float16* __restrict__ ws)
{
    __shared__ _Float16 Qs[64][LDP];   // [t][c]
    __shared__ _Float16 Ks[64][LDP];   // [s][c]
    __shared__ _Float16 Vs[64][LDP];   // [c][s]

    const int tid  = threadIdx.x;
    const int bh   = blockIdx.y;
    const int tile = blockIdx.x;       // 64-element tile along t/s
    const int x0   = tile * 64;

    const float qscale = 0.125f * 1.4426950408889634f * rescale[0];

    const float* qp = qkv + (size_t)(bh >> 3) * (1536 * T_LEN)
                          + (size_t)(bh & 7) * (192 * T_LEN);
    const float* kp = qp + 64 * T_LEN;
    const float* vp = qp + 128 * T_LEN;

    // Q,K: 4x4 register-block transpose [c][t] -> [t][c]
    {
        const int a4 = (tid & 15) * 4;
        const int c4 = (tid >> 4) * 4;
        float4 rq[4], rk[4];
#pragma unroll
        for (int i = 0; i < 4; ++i) {
            rq[i] = *(const float4*)(qp + (size_t)(c4 + i) * T_LEN + x0 + a4);
            rk[i] = *(const float4*)(kp + (size_t)(c4 + i) * T_LEN + x0 + a4);
        }
#pragma unroll
        for (int j = 0; j < 4; ++j) {
            half4 hq, hk;
#pragma unroll
            for (int i = 0; i < 4; ++i) {
                hq[i] = (_Float16)((&rq[i].x)[j] * qscale);
                hk[i] = (_Float16)((&rk[i].x)[j]);
            }
            *(half4*)&Qs[a4 + j][c4] = hq;
            *(half4*)&Ks[a4 + j][c4] = hk;
        }
        // V natural [c][s]
        const int s4 = (tid & 15) * 4;
        const int cv = tid >> 4;
#pragma unroll
        for (int i = 0; i < 4; ++i) {
            const int c = cv + 16 * i;
            float4 r = *(const float4*)(vp + (size_t)c * T_LEN + x0 + s4);
            half4 h; h[0]=(_Float16)r.x; h[1]=(_Float16)r.y; h[2]=(_Float16)r.z; h[3]=(_Float16)r.w;
            *(half4*)&Vs[c][s4] = h;
        }
    }
    __syncthreads();

    const int lane = tid & 63, wave = tid >> 6;
    const int l15 = lane & 15, quad = lane >> 4;
    _Float16* qf = ws;
    _Float16* kf = ws + (size_t)BH * FRAG_BH;
    _Float16* vf = ws + (size_t)2 * BH * FRAG_BH;

#pragma unroll
    for (int ks = 0; ks < 2; ++ks) {
        half8 hq = *(const half8*)&Qs[wave * 16 + l15][ks * 32 + quad * 8];
        half8 hk = *(const half8*)&Ks[wave * 16 + l15][ks * 32 + quad * 8];
        const size_t gqk = (((size_t)bh * 128 + tile * 4 + wave) * 2 + ks) * 512 + lane * 8;
        *(half8*)(qf + gqk) = hq;
        *(half8*)(kf + gqk) = hk;
    }
    // V fragments: wave w handles sl = tile*4 + w (16 s values)
#pragma unroll
    for (int ct = 0; ct < 4; ++ct) {
        half4 hv = *(const half4*)&Vs[ct * 16 + l15][wave * 16 + quad * 4];
        *(half4*)(vf + (size_t)bh * FRAG_BH
                     + ((size_t)(tile * 4 + wave) * 4 + ct) * 256 + lane * 4) = hv;
    }
}

// ---------------- pass 2: attention, s-partitioned waves, barrier-free loop --------
// R0-R5 post-mortem: every schedule hit ~48us because each wave privately consumed
// the full 16KB K+V tile per iteration (LDS pipe ~65-70% busy when staged; L1/VMEM
// equivalently bound when not) plus a P LDS round-trip. Fix is decomposition, not
// scheduling: wave w owns s-slice 16w of each 64-s tile.
//  - per-wave K/V reads drop 4x (2KB K + 2KB V per iter), direct from global
//    (slices are disjoint across waves -> staging has nothing to dedup) -> NO
//    barriers, NO LDS in the loop.
//  - with s=16/wave, PV uses mfma_f32_16x16x16f16 (k=s=16) and QK's D layout
//    (t=l15, s=quad*4+r) IS the PV B-frag layout (t=l15, k=quad*4+e): the whole
//    softmax stays in registers -- P transpose/LDS/permlane deleted entirely.
//  - denominator via f32 adds (ones-MFMAs deleted); O partials reduced across the
//    4 waves once at the end via chunked LDS (16KB), with 1/l folded in.
// XCD swizzle kept (FETCH 70->12.5MB verified). Grid 1024: bh pinned to one XCD.
__global__ __launch_bounds__(256, 3)
void attn_kernel(const _Float16* __restrict__ ws, float* __restrict__ out)
{
    __shared__ float Os[4][64][16];    // [wave][t][c16] reduction chunk (16KB)
    __shared__ float Lred[4][64];
    __shared__ float Lfin[64];

    const int tid  = threadIdx.x;
    const int wave = tid >> 6;
    const int lane = tid & 63;
    const int l15  = lane & 15;
    const int quad = lane >> 4;

    const int bid  = blockIdx.x;        // 0..1023
    const int xcd  = bid & 7;
    const int slot = bid >> 3;          // 0..127
    const int bh   = (slot & 3) * 8 + xcd;
    const int tile = slot >> 2;         // 0..31
    const int t0   = tile * QTILE;

    const _Float16* qf = ws;
    const _Float16* kf = ws + (size_t)BH * FRAG_BH;
    const _Float16* vf = ws + (size_t)2 * BH * FRAG_BH;
    float* op = out + (size_t)bh * (CH * T_LEN);

    // per-wave slice bases: sl(st) = st*4 + wave; sl-stride = 1024 halves
    const _Float16* kfp = kf + (size_t)bh * FRAG_BH + wave * 1024 + lane * 8;
    const _Float16* vfp = vf + (size_t)bh * FRAG_BH + wave * 1024 + lane * 4;

    // Q fragments: whole block's t range, persistent (same for all 4 waves -> L1)
    half8 bq[4][2];
#pragma unroll
    for (int tt = 0; tt < 4; ++tt)
#pragma unroll
        for (int ks = 0; ks < 2; ++ks)
            bq[tt][ks] = *(const half8*)(qf +
                (((size_t)bh * 128 + tile * 4 + tt) * 2 + ks) * 512 + lane * 8);

    const floatx4 fzero = {0.f, 0.f, 0.f, 0.f};
    floatx4 oacc[4][4];                 // [ct][tt]; c = ct*16+quad*4+r, t = tt*16+l15
#pragma unroll
    for (int ct = 0; ct < 4; ++ct)
#pragma unroll
        for (int tt = 0; tt < 4; ++tt) oacc[ct][tt] = fzero;
    float lsum[4] = {0.f, 0.f, 0.f, 0.f};   // per-lane partial denominators

    half8 akA[2], akB[2];    // K slice frags (A-operand, 16x16x32)
    half4 bvA[4], bvB[4];    // V slice frags (A-operand, 16x16x16)

    auto load_kv = [&](half8 (&ak)[2], half4 (&bv)[4], int st) {
        const _Float16* kp = kfp + (size_t)st * 4096;
        ak[0] = *(const half8*)kp;
        ak[1] = *(const half8*)(kp + 512);
        const _Float16* vp = vfp + (size_t)st * 4096;
#pragma unroll
        for (int ct = 0; ct < 4; ++ct)
            bv[ct] = *(const half4*)(vp + ct * 256);
    };

    // one s-tile: prefetch next slice, then per tt: QK -> exp (in-register) -> PV
    auto body = [&](half8 (&akC)[2], half4 (&bvC)[4],
                    half8 (&akN)[2], half4 (&bvN)[4], int st) {
        if (st < 31) load_kv(akN, bvN, st + 1);
#pragma unroll
        for (int tt = 0; tt < 4; ++tt) {
            floatx4 sacc = fzero;
#pragma unroll
            for (int ks = 0; ks < 2; ++ks)
                sacc = __builtin_amdgcn_mfma_f32_16x16x32_f16(
                    akC[ks], bq[tt][ks], sacc, 0, 0, 0);
            // lane owns P[t = tt*16+l15][s_local = quad*4 + r] -> exactly the
            // 16x16x16 B-frag (t = l15, k = quad*4 + e): zero data movement.
            float e0 = __builtin_amdgcn_exp2f(sacc[0]);
            float e1 = __builtin_amdgcn_exp2f(sacc[1]);
            float e2 = __builtin_amdgcn_exp2f(sacc[2]);
            float e3 = __builtin_amdgcn_exp2f(sacc[3]);
            lsum[tt] += (e0 + e1) + (e2 + e3);
            fp16x2 p01 = __builtin_amdgcn_cvt_pkrtz(e0, e1);
            fp16x2 p23 = __builtin_amdgcn_cvt_pkrtz(e2, e3);
            uintx2 uu;
            uu[0] = __builtin_bit_cast(unsigned, p01);
            uu[1] = __builtin_bit_cast(unsigned, p23);
            half4 pb = __builtin_bit_cast(half4, uu);
#pragma unroll
            for (int ct = 0; ct < 4; ++ct)
                oacc[ct][tt] = __builtin_amdgcn_mfma_f32_16x16x16f16(
                    bvC[ct], pb, oacc[ct][tt], 0, 0, 0);
        }
    };

    load_kv(akA, bvA, 0);
    for (int st = 0; st < 32; st += 2) {
        body(akA, bvA, akB, bvB, st);
        body(akB, bvB, akA, bvA, st + 1);
    }

    // ---- epilogue: cross-quad + cross-wave reduction of l and O, then store ------
    // quad-reduce lsum (lanes l, l^16, l^32, l^48 share t = l15)
#pragma unroll
    for (int tt = 0; tt < 4; ++tt) {
        float v = lsum[tt];
        v += __shfl_xor(v, 16, 64);
        v += __shfl_xor(v, 32, 64);
        lsum[tt] = v;
    }
    if (quad == 0) {
#pragma unroll
        for (int tt = 0; tt < 4; ++tt) Lred[wave][tt * 16 + l15] = lsum[tt];
    }
    __syncthreads();
    if (tid < 64)
        Lfin[tid] = (Lred[0][tid] + Lred[1][tid]) + (Lred[2][tid] + Lred[3][tid]);

    // O: reduce 4 wave-partials chunk-by-chunk over ct (16 c rows at a time)
    for (int ct = 0; ct < 4; ++ct) {
        __syncthreads();              // chunk-0: also publishes Lfin; later: Os reuse
#pragma unroll
        for (int tt = 0; tt < 4; ++tt)
            *(floatx4*)&Os[wave][tt * 16 + l15][quad * 4] = oacc[ct][tt];
        __syncthreads();
        const int t  = tid & 63;
        const int c4 = (tid >> 6) * 4;
        float4 s0 = *(const float4*)&Os[0][t][c4];
        float4 s1 = *(const float4*)&Os[1][t][c4];
        float4 s2 = *(const float4*)&Os[2][t][c4];
        float4 s3 = *(const float4*)&Os[3][t][c4];
        const float inv = 1.0f / Lfin[t];
#pragma unroll
        for (int j = 0; j < 4; ++j) {
            float v = (((&s0.x)[j] + (&s1.x)[j]) + ((&s2.x)[j] + (&s3.x)[j])) * inv;
            op[(size_t)(ct * 16 + c4 + j) * T_LEN + t0 + t] = v;
        }
    }
}

extern "C" void kernel_launch(void* const* d_in, const int* in_sizes, int n_in,
                              void* d_out, int out_size, void* d_ws, size_t ws_size,
                              hipStream_t stream) {
    const float* qkv     = (const float*)d_in[0];
    const float* rescale = (const float*)d_in[1];
    float* out = (float*)d_out;
    _Float16* ws = (_Float16*)d_ws;   // needs 3*32*131072*2 B = 25.2 MB

    prep_kernel<<<dim3(32, BH), dim3(256), 0, stream>>>(qkv, rescale, ws);
    attn_kernel<<<dim3(T_LEN / QTILE * BH), dim3(256), 0, stream>>>(ws, out);
}